// Round 2
// baseline (46.108 us; speedup 1.0000x reference)
//
#include <hip/hip_runtime.h>

#define NE 19
#define NEDGE (NE*NE)
#define CIN 64
#define PG 8
#define ROWS (NE*PG)      // 152 rows per block
#define MT 10             // ceil(152/16) m-tiles
#define NTHREADS 256
#define YSTRIDE 256       // bytes per LDS Y row (128 bf16: cols 0..63 = X@Wrel^T, 64..127 = X@Wroot^T)
#define APAD 20           // A row stride (floats); 80B = 16B-aligned rows

typedef float f32x4 __attribute__((ext_vector_type(4)));
typedef float f32x2 __attribute__((ext_vector_type(2)));
typedef unsigned short u16x2 __attribute__((ext_vector_type(2)));
typedef unsigned short u16x8 __attribute__((ext_vector_type(8)));
typedef __bf16 bf16x8 __attribute__((ext_vector_type(8)));

__device__ __forceinline__ unsigned short f2bf(float f) {
  unsigned u = __builtin_bit_cast(unsigned, f);
  return (unsigned short)((u + 0x7FFFu + ((u >> 16) & 1u)) >> 16);
}
__device__ __forceinline__ float bf2f(unsigned short h) {
  return __builtin_bit_cast(float, (unsigned)h << 16);
}
__device__ __forceinline__ int swz(int row, int byteoff) {
  return row * YSTRIDE + (byteoff ^ ((row & 7) << 4));
}

__global__ __launch_bounds__(NTHREADS, 4) void gconv_kernel(
    const float* __restrict__ x, const float* __restrict__ ew,
    const float* __restrict__ Wrel, const float* __restrict__ Wroot,
    const float* __restrict__ bias, float* __restrict__ out)
{
  __shared__ __align__(16) unsigned char Ys[ROWS * YSTRIDE];  // 38912 B
  __shared__ __align__(16) float Ap[NE][APAD];                // 1520 B; Ap[j][i] = softplus(ew[j*19+i])

  const int t = threadIdx.x;
  const int lane = t & 63;
  const int wv = t >> 6;
  const long long row0 = (long long)blockIdx.x * ROWS;

  // Phase 0: A matrix. edge e: src j=e/19, dst i=e%19 -> A[i][j]=sp(ew[e]) stored as Ap[j][i].
  for (int e = t; e < NEDGE; e += NTHREADS) {
    float z = ew[e];
    Ap[e / NE][e % NE] = fmaxf(z, 0.0f) + log1pf(expf(-fabsf(z)));
  }

  // B fragments for Y = X @ [Wrel^T | Wroot^T]  (K=64 input ch, N=128).
  // 16x16x32 B layout: n = nt*16 + (lane&15), k = kt*32 + (lane>>4)*8 + b
  u16x8 bfrag[2][8];
  {
    const int jl = lane & 15;
    const int k0 = (lane >> 4) * 8;
    #pragma unroll
    for (int kt = 0; kt < 2; ++kt)
      #pragma unroll
      for (int nt = 0; nt < 8; ++nt) {
        const float* Wsrc = (nt < 4) ? Wrel : Wroot;
        const float* q = Wsrc + ((nt & 3) * 16 + jl) * CIN + kt * 32 + k0;
        f32x4 a = *(const f32x4*)q;
        f32x4 b = *(const f32x4*)(q + 4);
        u16x8 h;
        h[0]=f2bf(a[0]); h[1]=f2bf(a[1]); h[2]=f2bf(a[2]); h[3]=f2bf(a[3]);
        h[4]=f2bf(b[0]); h[5]=f2bf(b[1]); h[6]=f2bf(b[2]); h[7]=f2bf(b[3]);
        bfrag[kt][nt] = h;
      }
  }

  // Phase 1: per m-tile, A-frags straight from GLOBAL (f32->bf16), 16 MFMA,
  // Y (bf16) -> LDS. No x staging, no pre-barrier.
  const float* xg = x + row0 * CIN;
  for (int mt = wv; mt < MT; mt += 4) {
    const int r0 = mt * 16;
    const int lr = lane & 15;
    const int hg = lane >> 4;
    int rr = r0 + lr; if (rr >= ROWS) rr = ROWS - 1;   // clamp tail (dup rows, discarded)
    const float* xp = xg + (long long)rr * CIN + hg * 8;
    u16x8 af[2];
    #pragma unroll
    for (int kt = 0; kt < 2; ++kt) {
      f32x4 a = *(const f32x4*)(xp + kt * 32);
      f32x4 b = *(const f32x4*)(xp + kt * 32 + 4);
      u16x8 h;
      h[0]=f2bf(a[0]); h[1]=f2bf(a[1]); h[2]=f2bf(a[2]); h[3]=f2bf(a[3]);
      h[4]=f2bf(b[0]); h[5]=f2bf(b[1]); h[6]=f2bf(b[2]); h[7]=f2bf(b[3]);
      af[kt] = h;
    }
    f32x4 acc[8];
    #pragma unroll
    for (int nt = 0; nt < 8; ++nt) { acc[nt][0]=0.f; acc[nt][1]=0.f; acc[nt][2]=0.f; acc[nt][3]=0.f; }
    #pragma unroll
    for (int kt = 0; kt < 2; ++kt)
      #pragma unroll
      for (int nt = 0; nt < 8; ++nt)
        acc[nt] = __builtin_amdgcn_mfma_f32_16x16x32_bf16(
            __builtin_bit_cast(bf16x8, af[kt]),
            __builtin_bit_cast(bf16x8, bfrag[kt][nt]), acc[nt], 0, 0, 0);
    // D: col = nt*16 + (lane&15), row = r0 + (lane>>4)*4 + b
    #pragma unroll
    for (int nt = 0; nt < 8; ++nt)
      #pragma unroll
      for (int b = 0; b < 4; ++b) {
        int row = r0 + hg * 4 + b;
        if (row < ROWS)
          *(unsigned short*)(&Ys[swz(row, 2 * (nt * 16 + lr))]) = f2bf(acc[nt][b]);
      }
  }
  __syncthreads();

  // Phase 2: mix. Thread = (graph g = t>>5, channel pair c2 = t&31).
  // out[g,i,c] = bias[c] + Y2[g,i,c] + sum_j Ap[j][i] * Y1[g,j,c]
  {
    const int g = t >> 5;
    const int c2 = t & 31;
    const int rb = g * NE;
    const float b0 = bias[c2 * 2];
    const float b1 = bias[c2 * 2 + 1];
    float acc[NE][2];
    #pragma unroll
    for (int i = 0; i < NE; ++i) {
      u16x2 v = *(const u16x2*)(&Ys[swz(rb + i, 128 + 4 * c2)]);
      acc[i][0] = b0 + bf2f(v[0]);
      acc[i][1] = b1 + bf2f(v[1]);
    }
    for (int j = 0; j < NE; ++j) {
      u16x2 v = *(const u16x2*)(&Ys[swz(rb + j, 4 * c2)]);
      float y0 = bf2f(v[0]), y1 = bf2f(v[1]);
      #pragma unroll
      for (int c = 0; c < 5; ++c) {
        f32x4 a4 = *(const f32x4*)(&Ap[j][c * 4]);
        #pragma unroll
        for (int ii = 0; ii < 4; ++ii) {
          int i = c * 4 + ii;
          if (i < NE) {
            acc[i][0] = fmaf(a4[ii], y0, acc[i][0]);
            acc[i][1] = fmaf(a4[ii], y1, acc[i][1]);
          }
        }
      }
    }
    #pragma unroll
    for (int i = 0; i < NE; ++i) {
      f32x2 st; st[0] = acc[i][0]; st[1] = acc[i][1];
      *(f32x2*)(out + (row0 + rb + i) * 64 + c2 * 2) = st;
    }
  }
}

extern "C" void kernel_launch(void* const* d_in, const int* in_sizes, int n_in,
                              void* d_out, int out_size, void* d_ws, size_t ws_size,
                              hipStream_t stream) {
  const float* x    = (const float*)d_in[0];
  const float* ew   = (const float*)d_in[1];
  const float* Wrel = (const float*)d_in[2];
  const float* Wroot= (const float*)d_in[3];
  const float* bias = (const float*)d_in[4];
  float* out = (float*)d_out;
  const int ngraphs = (in_sizes[0] / CIN) / NE;   // 8192
  const int nblocks = ngraphs / PG;               // 1024
  gconv_kernel<<<nblocks, NTHREADS, 0, stream>>>(x, ew, Wrel, Wroot, bias, out);
}